// Round 7
// baseline (186.062 us; speedup 1.0000x reference)
//
#include <hip/hip_runtime.h>
#include <math.h>

#define C_DIM 256
#define N_DIM 4096
#define B_DIM 8

typedef __attribute__((ext_vector_type(8))) short bf16x8;
typedef __attribute__((ext_vector_type(4))) float f32x4;
typedef __attribute__((ext_vector_type(8))) unsigned short us8;
typedef __attribute__((ext_vector_type(4))) unsigned short us4;

__device__ inline unsigned short f2bf(float f) {
    unsigned int u = __float_as_uint(f);
    u += 0x7fffu + ((u >> 16) & 1u);       // round-to-nearest-even
    return (unsigned short)(u >> 16);
}

__device__ inline void gload_lds16(const void* g, void* l) {
    __builtin_amdgcn_global_load_lds(
        (const __attribute__((address_space(1))) unsigned int*)g,
        (__attribute__((address_space(3))) unsigned int*)l, 16, 0, 0);
}

// ---------------- prep: weight cvt + bias concat + gn per-channel stats ----------------
__global__ __launch_bounds__(256) void prep_kernel(
    const float* __restrict__ wq, const float* __restrict__ wk,
    const float* __restrict__ wv, const float* __restrict__ wo,
    const float* __restrict__ bk, const float* __restrict__ bv,
    const float* __restrict__ x,
    unsigned short* __restrict__ wqb, unsigned short* __restrict__ wkvb,
    unsigned short* __restrict__ wob, float* __restrict__ bkv,
    float2* __restrict__ sums)
{
    int z = blockIdx.x;
    int t = threadIdx.x;
    if (z < 256) {
        const float* s; unsigned short* d;
        int which = z >> 6;
        if (which == 0)      { s = wq; d = wqb; }
        else if (which == 1) { s = wk; d = wkvb; }
        else if (which == 2) { s = wv; d = wkvb + 65536; }
        else                 { s = wo; d = wob; }
        int idx = (z & 63) * 1024 + t * 4;
        float4 v = *(const float4*)(s + idx);
        us4 r; r[0] = f2bf(v.x); r[1] = f2bf(v.y); r[2] = f2bf(v.z); r[3] = f2bf(v.w);
        *(us4*)(d + idx) = r;
    } else if (z == 256) {
        bkv[t]       = bk[t];
        bkv[t + 256] = bv[t];
    } else {
        int bc = z - 257;
        const float* xc = x + (size_t)bc * N_DIM;
        float s = 0.f, q = 0.f;
        for (int i = t; i < 1024; i += 256) {
            float4 v = ((const float4*)xc)[i];
            s += v.x + v.y + v.z + v.w;
            q += v.x*v.x + v.y*v.y + v.z*v.z + v.w*v.w;
        }
        #pragma unroll
        for (int off = 32; off > 0; off >>= 1) {
            s += __shfl_down(s, off);
            q += __shfl_down(q, off);
        }
        __shared__ float red[8];
        int w = t >> 6;
        if ((t & 63) == 0) { red[w*2] = s; red[w*2+1] = q; }
        __syncthreads();
        if (t == 0) {
            sums[bc] = make_float2(red[0]+red[2]+red[4]+red[6],
                                   red[1]+red[3]+red[5]+red[7]);
        }
    }
}

// ---------------- GroupNorm apply + transpose -> bf16 hT[b][n][c] ----------------
__global__ __launch_bounds__(256) void gn_apply(const float* __restrict__ x,
                                                const float2* __restrict__ sums,
                                                const float* __restrict__ gamma,
                                                const float* __restrict__ beta,
                                                unsigned short* __restrict__ hT) {
    int b = blockIdx.y, n0 = blockIdx.x * 64;
    int t = threadIdx.x;
    __shared__ float scale[256], shift[256];
    __shared__ unsigned short trans[64][264];

    {
        int c = t;
        int gbase = c & ~7;
        float s = 0.f, q = 0.f;
        #pragma unroll
        for (int j = 0; j < 8; j++) {
            float2 u = sums[b*256 + gbase + j];
            s += u.x; q += u.y;
        }
        float mean = s * (1.f/32768.f);
        float var  = q * (1.f/32768.f) - mean*mean;
        float inv  = rsqrtf(var + 1e-6f);
        float gm = gamma[c] * inv;
        scale[c] = gm;
        shift[c] = beta[c] - mean * gm;
    }
    __syncthreads();

    #pragma unroll
    for (int it = 0; it < 16; it++) {
        int c  = it*16 + (t >> 4);
        int nl = (t & 15) * 4;
        float4 v = *(const float4*)(x + ((size_t)(b*C_DIM + c))*N_DIM + n0 + nl);
        float sc = scale[c], sh = shift[c];
        trans[nl+0][c] = f2bf(v.x*sc + sh);
        trans[nl+1][c] = f2bf(v.y*sc + sh);
        trans[nl+2][c] = f2bf(v.z*sc + sh);
        trans[nl+3][c] = f2bf(v.w*sc + sh);
    }
    __syncthreads();

    #pragma unroll
    for (int it = 0; it < 8; it++) {
        int nl = it*8 + (t >> 5);
        int cb = (t & 31) * 8;
        us8 vv = *(us8*)&trans[nl][cb];
        *(us8*)(hT + ((size_t)b*N_DIM + n0 + nl)*C_DIM + cb) = vv;
    }
}

// ---------------- kv split-K reduce + cvt (8 splits) ----------------
__global__ __launch_bounds__(256) void kvred(const float* __restrict__ src, unsigned short* __restrict__ dst) {
    int gi = (blockIdx.x * 256 + threadIdx.x) * 4;
    int b = gi >> 16, idx = gi & 65535;
    float4 a = make_float4(0.f,0.f,0.f,0.f);
    #pragma unroll
    for (int sp = 0; sp < 8; sp++) {
        float4 v = *(const float4*)(src + (((size_t)b*8 + sp) << 16) + idx);
        a.x += v.x; a.y += v.y; a.z += v.z; a.w += v.w;
    }
    us4 r; r[0] = f2bf(a.x); r[1] = f2bf(a.y); r[2] = f2bf(a.z); r[3] = f2bf(a.w);
    *(us4*)(dst + ((size_t)b << 16) + idx) = r;
}

// ================= qkv2: big-tile NT GEMM body for the QKV projections =================
// Tile M x N with M=RI*32, N=RJ*32, K=256 (8 steps of BK=32), 4 waves (2x2),
// wave-tile (RI*16) x (RJ*16), 32 MFMAs per K-step (2x the 128^2 body).
// Counted-vmcnt depth-2 pipeline, triple-buffered LDS (3 x 24KB = 72KB),
// both-sides chunk swizzle (verified R4: conflict-free-ish staging/read pair).
// MODE 0: Q  — bias[col] + elu, C row stride 256
// MODE 1: KV — bias[global row] + optional elu, C row stride 4096
template<int RI, int RJ, int MODE>
__device__ __forceinline__ void gemm2_body(
    const unsigned short* __restrict__ Ab,   // pre-offset: tile rows [0,M) x K=256
    const unsigned short* __restrict__ Bb,   // pre-offset: tile rows [0,N) x K=256
    const float* __restrict__ bias,
    unsigned short* __restrict__ Cp,         // output base (batch)
    int crow0, int ccol0, bool elu, char* smem)
{
    constexpr int M = RI * 32, N = RJ * 32;
    constexpr int ACH = M / 64;              // per-thread A chunks per stage
    constexpr int BCH = N / 64;              // per-thread B chunks per stage
    unsigned short* lds = (unsigned short*)smem;

    int t = threadIdx.x;
    int w = t >> 6, l = t & 63;
    int wm = w >> 1, wn = w & 1;
    int l15 = l & 15, quad = l >> 4;

    f32x4 acc[RI][RJ];
    #pragma unroll
    for (int i = 0; i < RI; i++)
        #pragma unroll
        for (int j = 0; j < RJ; j++)
            #pragma unroll
            for (int r = 0; r < 4; r++) acc[i][j][r] = 0.f;

    // stage one BK=32 K-tile into buffer buf (A region M*32, B region N*32 shorts)
    auto stage = [&](int buf, int kt) {
        unsigned short* Ls = lds + buf * (M*32 + N*32);
        #pragma unroll
        for (int s = 0; s < ACH; s++) {
            int c = t + s*256, row = c >> 2;
            int cs = (c & 3) ^ ((row >> 1) & 3);
            gload_lds16(Ab + (size_t)row*256 + kt + cs*8, Ls + c*8);
        }
        #pragma unroll
        for (int s = 0; s < BCH; s++) {
            int c = t + s*256, row = c >> 2;
            int cs = (c & 3) ^ ((row >> 1) & 3);
            gload_lds16(Bb + (size_t)row*256 + kt + cs*8, Ls + M*32 + c*8);
        }
    };

    stage(0, 0);
    stage(1, 32);

    int acol = (quad ^ ((l15 >> 1) & 3)) * 8;   // swizzled LDS read column

    int bufc = 0;
    for (int kt = 0; kt < 8; ++kt) {
        if (kt + 1 < 8) asm volatile("s_waitcnt vmcnt(6)" ::: "memory");
        else            asm volatile("s_waitcnt vmcnt(0)" ::: "memory");
        __builtin_amdgcn_s_barrier();
        __builtin_amdgcn_sched_barrier(0);
        if (kt + 2 < 8) {
            int bufn = bufc + 2; if (bufn >= 3) bufn -= 3;
            stage(bufn, (kt + 2) * 32);
        }
        __builtin_amdgcn_sched_barrier(0);

        const unsigned short* As = lds + bufc * (M*32 + N*32);
        const unsigned short* Bs = As + M*32;
        bf16x8 af[RI], bfr[RJ];
        #pragma unroll
        for (int i = 0; i < RI; i++)
            af[i]  = *(const bf16x8*)(As + (wm*(RI*16) + i*16 + l15)*32 + acol);
        #pragma unroll
        for (int j = 0; j < RJ; j++)
            bfr[j] = *(const bf16x8*)(Bs + (wn*(RJ*16) + j*16 + l15)*32 + acol);
        __builtin_amdgcn_s_setprio(1);
        #pragma unroll
        for (int i = 0; i < RI; i++)
            #pragma unroll
            for (int j = 0; j < RJ; j++)
                acc[i][j] = __builtin_amdgcn_mfma_f32_16x16x32_bf16(af[i], bfr[j], acc[i][j], 0, 0, 0);
        __builtin_amdgcn_s_setprio(0);
        bufc = (bufc == 2) ? 0 : bufc + 1;
    }
    __syncthreads();   // epilogue reuses staging LDS

    if (MODE == 0) {
        // 128x256 tile -> two 64-row halves; ep[64][264]
        unsigned short* ep = (unsigned short*)smem;
        #pragma unroll
        for (int h = 0; h < 2; h++) {
            if (wm == h) {
                #pragma unroll
                for (int i = 0; i < RI; i++) {
                    #pragma unroll
                    for (int j = 0; j < RJ; j++) {
                        int cl = wn*128 + j*16 + l15;
                        float bi = bias[cl];
                        #pragma unroll
                        for (int r = 0; r < 4; r++) {
                            int rl = quad*4 + i*16 + r;
                            float val = acc[i][j][r] + bi;
                            val = val > 0.f ? val + 1.f : __expf(val);
                            ep[rl*264 + cl] = f2bf(val);
                        }
                    }
                }
            }
            __syncthreads();
            #pragma unroll
            for (int it = 0; it < 8; it++) {
                int row = it*8 + (t >> 5);
                int colc = (t & 31) * 8;
                us8 vv = *(us8*)(ep + row*264 + colc);
                *(us8*)(Cp + (size_t)(crow0 + h*64 + row)*256 + colc) = vv;
            }
            __syncthreads();
        }
    } else {
        // 256x128 tile -> two 128-row halves; ep[128][136]
        unsigned short* ep = (unsigned short*)smem;
        #pragma unroll
        for (int h = 0; h < 2; h++) {
            if (wm == h) {
                #pragma unroll
                for (int i = 0; i < RI; i++) {
                    #pragma unroll
                    for (int j = 0; j < RJ; j++) {
                        int cl = wn*64 + j*16 + l15;
                        #pragma unroll
                        for (int r = 0; r < 4; r++) {
                            int rl = quad*4 + i*16 + r;
                            float val = acc[i][j][r] + bias[crow0 + h*128 + rl];
                            if (elu) val = val > 0.f ? val + 1.f : __expf(val);
                            ep[rl*136 + cl] = f2bf(val);
                        }
                    }
                }
            }
            __syncthreads();
            #pragma unroll
            for (int it = 0; it < 8; it++) {
                int row = it*16 + (t >> 4);
                int colc = (t & 15) * 8;
                us8 vv = *(us8*)(ep + row*136 + colc);
                *(us8*)(Cp + (size_t)(crow0 + h*128 + row)*4096 + ccol0 + colc) = vv;
            }
            __syncthreads();
        }
    }
}

// grid 768: z<256 -> Q blocks (tile 128x256); else K/V blocks (tile 256x128)
__global__ __launch_bounds__(256, 2) void qkv2(
    const unsigned short* __restrict__ hT, const unsigned short* __restrict__ wqb,
    const unsigned short* __restrict__ wkvb,
    const float* __restrict__ bq, const float* __restrict__ bkv,
    unsigned short* __restrict__ qT, unsigned short* __restrict__ kvbuf)
{
    __shared__ __align__(16) char smem[73728];   // 3 x 24KB staging; epilogue reuses
    int z = blockIdx.x;
    if (z < 256) {
        int b = z >> 5, m_blk = (z & 31) * 128;
        gemm2_body<4,8,0>(hT + (size_t)b*1048576 + (size_t)m_blk*256, wqb,
                          bq, qT + (size_t)b*1048576, m_blk, 0, true, smem);
    } else {
        int iz = z - 256;
        int b = iz >> 6, rem = iz & 63;
        int mh = rem >> 5, n_blk = (rem & 31) * 128;
        gemm2_body<8,4,1>(wkvb + (size_t)mh*65536,
                          hT + (size_t)b*1048576 + (size_t)n_blk*256,
                          bkv, kvbuf + (size_t)b*2097152,
                          mh*256, n_blk, mh == 0, smem);
    }
}

// ================= shared NT bf16 MFMA GEMM body (modes 3,4,5) =================
// 128x128 tile, BK=32, 4 waves, depth-2 counted-vmcnt pipeline, triple-buffered LDS,
// both-sides chunk swizzle.
template<int MODE>
__device__ __forceinline__ void gemm_body(
    const unsigned short* __restrict__ Ab, const unsigned short* __restrict__ Bb,
    const float* __restrict__ bias, const float* __restrict__ residb,
    void* __restrict__ Cb,
    int N, int K, int k0, int Ks, int m_blk, int n_blk, char* smem)
{
    unsigned short* lds = (unsigned short*)smem;

    int t = threadIdx.x;
    int w = t >> 6, l = t & 63;
    int wm = w >> 1, wn = w & 1;
    int l15 = l & 15, quad = l >> 4;

    int srow = w * 16 + (l >> 2);
    int skc  = (((l & 3) ^ ((l >> 3) & 3)) * 8);

    f32x4 acc[4][4];
    #pragma unroll
    for (int i = 0; i < 4; i++)
        #pragma unroll
        for (int j = 0; j < 4; j++)
            #pragma unroll
            for (int r = 0; r < 4; r++) acc[i][j][r] = 0.f;

    auto stage = [&](int buf, int kt) {
        unsigned short* Asl = lds + buf*8192 + t*8;
        unsigned short* Bsl = Asl + 4096;
        #pragma unroll
        for (int rep = 0; rep < 2; rep++) {
            gload_lds16(Ab + (size_t)(m_blk + rep*64 + srow) * K + kt + skc, Asl + rep*2048);
            gload_lds16(Bb + (size_t)(n_blk + rep*64 + srow) * K + kt + skc, Bsl + rep*2048);
        }
    };

    const int nt = Ks >> 5;

    stage(0, k0);
    if (nt > 1) stage(1, k0 + 32);

    int acol = (quad ^ ((l15 >> 1) & 3)) * 8;

    int bufc = 0;
    for (int kt = 0; kt < nt; ++kt) {
        if (kt + 1 < nt) asm volatile("s_waitcnt vmcnt(4)" ::: "memory");
        else             asm volatile("s_waitcnt vmcnt(0)" ::: "memory");
        __builtin_amdgcn_s_barrier();
        __builtin_amdgcn_sched_barrier(0);
        if (kt + 2 < nt) {
            int bufn = bufc + 2; if (bufn >= 3) bufn -= 3;
            stage(bufn, k0 + (kt + 2) * 32);
        }
        __builtin_amdgcn_sched_barrier(0);

        const unsigned short* Aw = lds + bufc*8192 + (wm*64 + l15)*32 + acol;
        const unsigned short* Bw = lds + bufc*8192 + 4096 + (wn*64 + l15)*32 + acol;
        bf16x8 af[4], bfr[4];
        #pragma unroll
        for (int i = 0; i < 4; i++) af[i]  = *(const bf16x8*)(Aw + i*512);
        #pragma unroll
        for (int j = 0; j < 4; j++) bfr[j] = *(const bf16x8*)(Bw + j*512);
        __builtin_amdgcn_s_setprio(1);
        #pragma unroll
        for (int i = 0; i < 4; i++)
            #pragma unroll
            for (int j = 0; j < 4; j++)
                acc[i][j] = __builtin_amdgcn_mfma_f32_16x16x32_bf16(af[i], bfr[j], acc[i][j], 0, 0, 0);
        __builtin_amdgcn_s_setprio(0);
        bufc = (bufc == 2) ? 0 : bufc + 1;
    }
    __syncthreads();

    if (MODE == 4) {
        unsigned short* ep = (unsigned short*)smem;
        unsigned short* Cp = (unsigned short*)Cb;
        #pragma unroll
        for (int h = 0; h < 2; h++) {
            if (wm == h) {
                int row0 = quad*4;
                int col0 = wn*64 + l15;
                #pragma unroll
                for (int i = 0; i < 4; i++)
                    #pragma unroll
                    for (int j = 0; j < 4; j++)
                        #pragma unroll
                        for (int r = 0; r < 4; r++)
                            ep[(row0 + i*16 + r)*136 + col0 + j*16] = f2bf(acc[i][j][r]);
            }
            __syncthreads();
            #pragma unroll
            for (int it = 0; it < 4; it++) {
                int row = it*16 + (t >> 4);
                int col = (t & 15) * 8;
                us8 vv = *(us8*)(ep + row*136 + col);
                *(us8*)(Cp + (size_t)(m_blk + h*64 + row) * N + n_blk + col) = vv;
            }
            __syncthreads();
        }
    } else {
        float* ep32 = (float*)smem;
        float* Cp = (float*)Cb;
        #pragma unroll
        for (int h = 0; h < 2; h++) {
            if (wm == h) {
                int row0 = quad*4;
                int col0 = wn*64 + l15;
                #pragma unroll
                for (int i = 0; i < 4; i++)
                    #pragma unroll
                    for (int j = 0; j < 4; j++)
                        #pragma unroll
                        for (int r = 0; r < 4; r++)
                            ep32[(row0 + i*16 + r)*140 + col0 + j*16] = acc[i][j][r];
            }
            __syncthreads();
            #pragma unroll
            for (int it = 0; it < 8; it++) {
                int rl  = it*8 + (t >> 5);
                int row = m_blk + h*64 + rl;
                int col = (t & 31) * 4;
                f32x4 vv = *(f32x4*)(ep32 + rl*140 + col);
                if (MODE == 5) {
                    float bi = bias[row];
                    float4 rv = *(const float4*)(residb + (size_t)row * N + n_blk + col);
                    vv[0] += bi + rv.x; vv[1] += bi + rv.y;
                    vv[2] += bi + rv.z; vv[3] += bi + rv.w;
                }
                *(f32x4*)(Cp + (size_t)row * N + n_blk + col) = vv;
            }
            __syncthreads();
        }
    }
}

template<int MODE>
__global__ __launch_bounds__(256) void gemm_nt(
    const unsigned short* __restrict__ A, const unsigned short* __restrict__ B,
    const float* __restrict__ bias, const float* __restrict__ resid,
    void* __restrict__ Cout,
    int N, int K, int splits,
    size_t sA, size_t sB, size_t sC, size_t sR, int elem4)
{
    __shared__ __align__(16) char smem[49152];
    int b  = blockIdx.z / splits;
    int sp = blockIdx.z % splits;
    int Ks = K / splits;
    size_t cbase = (MODE == 3) ? ((size_t)(b*splits + sp)) * sC : (size_t)b * sC;
    void* Cb = elem4 ? (void*)((float*)Cout + cbase) : (void*)((unsigned short*)Cout + cbase);
    gemm_body<MODE>(A + b*sA, B + b*sB, bias,
                    resid ? resid + b*sR : nullptr, Cb,
                    N, K, sp*Ks, Ks, blockIdx.y*128, blockIdx.x*128, smem);
}

extern "C" void kernel_launch(void* const* d_in, const int* in_sizes, int n_in,
                              void* d_out, int out_size, void* d_ws, size_t ws_size,
                              hipStream_t stream) {
    const float* x     = (const float*)d_in[0];
    const float* gamma = (const float*)d_in[1];
    const float* beta  = (const float*)d_in[2];
    const float* wq    = (const float*)d_in[3];
    const float* bq    = (const float*)d_in[4];
    const float* wk    = (const float*)d_in[5];
    const float* bk    = (const float*)d_in[6];
    const float* wv    = (const float*)d_in[7];
    const float* bv    = (const float*)d_in[8];
    const float* wo    = (const float*)d_in[9];
    const float* bo    = (const float*)d_in[10];
    float* out = (float*)d_out;

    const size_t TEN = (size_t)B_DIM * C_DIM * N_DIM;   // 8,388,608 elems
    unsigned short* ws16  = (unsigned short*)d_ws;
    unsigned short* hT    = ws16;                    // [B][N][C] bf16
    unsigned short* qT    = hT    + TEN;             // [B][N][C] bf16
    unsigned short* kvbuf = qT    + TEN;             // [B][512][N] bf16 (k rows 0-255, v rows 256-511)
    unsigned short* kvb   = kvbuf + 2*TEN;           // [B][C][C] bf16
    unsigned short* M2b   = kvb   + 524288;          // [B][C][C] bf16
    unsigned short* wqb   = M2b   + 524288;
    unsigned short* wkvb  = wqb   + 65536;           // stacked [512][256]
    unsigned short* wob   = wkvb  + 131072;
    float*          bkv   = (float*)(wob + 65536);   // [512]
    float2*         sums  = (float2*)(bkv + 512);    // [B*C]
    float*          kvf   = (float*)(sums + 2048);   // [B][8][C*C] fp32 partials (16.8MB)

    // 1) prep: weights->bf16, bias concat, gn stats
    prep_kernel<<<dim3(2305), 256, 0, stream>>>(wq, wk, wv, wo, bk, bv, x,
                                                wqb, wkvb, wob, bkv, sums);
    // 2) groupnorm apply -> hT
    gn_apply<<<dim3(N_DIM/64, B_DIM), 256, 0, stream>>>(x, sums, gamma, beta, hT);
    // 3) big-tile q/k/v projections
    qkv2<<<dim3(768), 256, 0, stream>>>(hT, wqb, wkvb, bq, bkv, qT, kvbuf);
    // 4) kv[c][d] = sum_n k[c][n]*v[d][n]  M=256 N=256 K=4096, split-8 fp32
    gemm_nt<3><<<dim3(2, 2, B_DIM*8), 256, 0, stream>>>(
        kvbuf, kvbuf + 1048576, nullptr, nullptr, kvf,
        256, 4096, 8, 2097152, 2097152, 65536, 0, 1);
    // 5) reduce 8 partials -> kvb bf16
    kvred<<<dim3(512), 256, 0, stream>>>(kvf, kvb);
    // 6) M2[o][c] = sum_d wo[o][d]*kv[c][d]  M=256 N=256 K=256
    gemm_nt<4><<<dim3(2, 2, B_DIM), 256, 0, stream>>>(
        wob, kvb, nullptr, nullptr, M2b,
        256, 256, 1, 0, 65536, 65536, 0, 0);
    // 7) out[o][n] = sum_c M2[o][c]*qT[n][c] + bo[o] + x  M=256 N=4096 K=256
    gemm_nt<5><<<dim3(32, 2, B_DIM), 256, 0, stream>>>(
        M2b, qT, bo, x, out,
        4096, 256, 1, 65536, 1048576, 1048576, 1048576, 1);
}

// Round 8
// 173.874 us; speedup vs baseline: 1.0701x; 1.0701x over previous
//
#include <hip/hip_runtime.h>
#include <math.h>

#define C_DIM 256
#define N_DIM 4096
#define B_DIM 8

typedef __attribute__((ext_vector_type(8))) short bf16x8;
typedef __attribute__((ext_vector_type(4))) float f32x4;
typedef __attribute__((ext_vector_type(8))) unsigned short us8;
typedef __attribute__((ext_vector_type(4))) unsigned short us4;

__device__ inline unsigned short f2bf(float f) {
    unsigned int u = __float_as_uint(f);
    u += 0x7fffu + ((u >> 16) & 1u);       // round-to-nearest-even
    return (unsigned short)(u >> 16);
}

__device__ inline void gload_lds16(const void* g, void* l) {
    __builtin_amdgcn_global_load_lds(
        (const __attribute__((address_space(1))) unsigned int*)g,
        (__attribute__((address_space(3))) unsigned int*)l, 16, 0, 0);
}

// ---------------- prep: weight cvt + bias concat + gn per-channel stats ----------------
__global__ __launch_bounds__(256) void prep_kernel(
    const float* __restrict__ wq, const float* __restrict__ wk,
    const float* __restrict__ wv, const float* __restrict__ wo,
    const float* __restrict__ bk, const float* __restrict__ bv,
    const float* __restrict__ x,
    unsigned short* __restrict__ wqb, unsigned short* __restrict__ wkvb,
    unsigned short* __restrict__ wob, float* __restrict__ bkv,
    float2* __restrict__ sums)
{
    int z = blockIdx.x;
    int t = threadIdx.x;
    if (z < 256) {
        const float* s; unsigned short* d;
        int which = z >> 6;
        if (which == 0)      { s = wq; d = wqb; }
        else if (which == 1) { s = wk; d = wkvb; }
        else if (which == 2) { s = wv; d = wkvb + 65536; }
        else                 { s = wo; d = wob; }
        int idx = (z & 63) * 1024 + t * 4;
        float4 v = *(const float4*)(s + idx);
        us4 r; r[0] = f2bf(v.x); r[1] = f2bf(v.y); r[2] = f2bf(v.z); r[3] = f2bf(v.w);
        *(us4*)(d + idx) = r;
    } else if (z == 256) {
        bkv[t]       = bk[t];
        bkv[t + 256] = bv[t];
    } else {
        int bc = z - 257;
        const float* xc = x + (size_t)bc * N_DIM;
        float s = 0.f, q = 0.f;
        for (int i = t; i < 1024; i += 256) {
            float4 v = ((const float4*)xc)[i];
            s += v.x + v.y + v.z + v.w;
            q += v.x*v.x + v.y*v.y + v.z*v.z + v.w*v.w;
        }
        #pragma unroll
        for (int off = 32; off > 0; off >>= 1) {
            s += __shfl_down(s, off);
            q += __shfl_down(q, off);
        }
        __shared__ float red[8];
        int w = t >> 6;
        if ((t & 63) == 0) { red[w*2] = s; red[w*2+1] = q; }
        __syncthreads();
        if (t == 0) {
            sums[bc] = make_float2(red[0]+red[2]+red[4]+red[6],
                                   red[1]+red[3]+red[5]+red[7]);
        }
    }
}

// ---------------- kv split-K reduce + cvt (8 splits) ----------------
__global__ __launch_bounds__(256) void kvred(const float* __restrict__ src, unsigned short* __restrict__ dst) {
    int gi = (blockIdx.x * 256 + threadIdx.x) * 4;
    int b = gi >> 16, idx = gi & 65535;
    float4 a = make_float4(0.f,0.f,0.f,0.f);
    #pragma unroll
    for (int sp = 0; sp < 8; sp++) {
        float4 v = *(const float4*)(src + (((size_t)b*8 + sp) << 16) + idx);
        a.x += v.x; a.y += v.y; a.z += v.z; a.w += v.w;
    }
    us4 r; r[0] = f2bf(a.x); r[1] = f2bf(a.y); r[2] = f2bf(a.z); r[3] = f2bf(a.w);
    *(us4*)(dst + ((size_t)b << 16) + idx) = r;
}

// ================= fused GN + transpose + Q/K/V projections =================
// One block per (batch b, 64-wide n-slice). LDS: hs = GN'd bf16 h tile [64 n][256 c]
// (chunk-swizzled: cs = (chunk&~3)|((chunk&3)^((n>>1)&3))), wst = 2x16KB weight staging
// (R4 involution: stage src chunk = slot^((row>>1)&3), read col = quad^((l15>>1)&3)).
// Phases: GN-fill -> K (wk, elu) -> V (wv) -> Q (wq, elu), all K=256 in 8 BK=32 steps,
// 4 waves (2x2). Epilogues bounce through wst for coalesced us8 stores.

__device__ __forceinline__ void stage_w(const unsigned short* __restrict__ W,
                                        unsigned short* __restrict__ dst, int kt, int t) {
    #pragma unroll
    for (int s = 0; s < 4; s++) {
        int c = t + s*256;            // 0..1023 16B-chunks
        int row = c >> 2, slot = c & 3;
        int cs = slot ^ ((row >> 1) & 3);
        gload_lds16(W + (size_t)row*256 + kt + cs*8, dst + c*8);
    }
}

// K/V phase: out rows cc in [ccb,ccb+256), cols n0+[0,64). A = staged weights (m-side),
// B = hs (n-side). Wave tile 128x32: acc[8][2].
__device__ __forceinline__ void phase_kv(
    const unsigned short* __restrict__ W, const unsigned short* __restrict__ hs,
    unsigned short* __restrict__ wst, unsigned short* __restrict__ kvdst,
    const float* __restrict__ biasr, int ccb, int n0, bool elu, int t)
{
    int w = t >> 6, l = t & 63;
    int wm = w >> 1, wn = w & 1;
    int l15 = l & 15, quad = l >> 4;
    int acol = (quad ^ ((l15 >> 1) & 3)) * 8;
    int rsw  = (l15 >> 1) & 3;

    f32x4 acc[8][2];
    #pragma unroll
    for (int i = 0; i < 8; i++)
        #pragma unroll
        for (int j = 0; j < 2; j++)
            #pragma unroll
            for (int r = 0; r < 4; r++) acc[i][j][r] = 0.f;

    stage_w(W, wst, 0, t);
    asm volatile("s_waitcnt vmcnt(0)" ::: "memory");
    __syncthreads();

    int buf = 0;
    for (int kt = 0; kt < 8; ++kt) {
        if (kt + 1 < 8) stage_w(W, wst + (buf^1)*8192, (kt+1)*32, t);
        __builtin_amdgcn_sched_barrier(0);
        bf16x8 af[8], bfr[2];
        #pragma unroll
        for (int i = 0; i < 8; i++)
            af[i] = *(const bf16x8*)(wst + buf*8192 + (wm*128 + i*16 + l15)*32 + acol);
        #pragma unroll
        for (int j = 0; j < 2; j++) {
            int n = wn*32 + j*16 + l15;
            bfr[j] = *(const bf16x8*)(hs + n*256 + (kt*4 + (quad ^ rsw))*8);
        }
        __builtin_amdgcn_s_setprio(1);
        #pragma unroll
        for (int i = 0; i < 8; i++)
            #pragma unroll
            for (int j = 0; j < 2; j++)
                acc[i][j] = __builtin_amdgcn_mfma_f32_16x16x32_bf16(af[i], bfr[j], acc[i][j], 0, 0, 0);
        __builtin_amdgcn_s_setprio(0);
        __builtin_amdgcn_sched_barrier(0);
        asm volatile("s_waitcnt vmcnt(0)" ::: "memory");
        __syncthreads();
        buf ^= 1;
    }

    // epilogue: two 128-row halves bounced through wst (ep[128][72] = 18.4KB)
    unsigned short* ep = wst;
    #pragma unroll
    for (int h = 0; h < 2; h++) {
        if (wm == h) {
            #pragma unroll
            for (int i = 0; i < 8; i++) {
                #pragma unroll
                for (int j = 0; j < 2; j++) {
                    int cl = wn*32 + j*16 + l15;
                    #pragma unroll
                    for (int r = 0; r < 4; r++) {
                        int rloc = i*16 + quad*4 + r;
                        float val = acc[i][j][r] + biasr[h*128 + rloc];
                        if (elu) val = val > 0.f ? val + 1.f : __expf(val);
                        ep[rloc*72 + cl] = f2bf(val);
                    }
                }
            }
        }
        __syncthreads();
        #pragma unroll
        for (int it = 0; it < 4; it++) {
            int idx = t + it*256;         // 0..1023
            int row = idx >> 3;           // 0..127
            int colc = (idx & 7) * 8;     // 0..56
            us8 vv = *(us8*)(ep + row*72 + colc);
            *(us8*)(kvdst + (size_t)(ccb + h*128 + row)*4096 + n0 + colc) = vv;
        }
        __syncthreads();
    }
}

// Q phase: out rows n0+[0,64), cols o in [0,256). A = hs (m-side n), B = staged wq.
// Wave tile 32x128: acc[2][8].
__device__ __forceinline__ void phase_q(
    const unsigned short* __restrict__ W, const unsigned short* __restrict__ hs,
    unsigned short* __restrict__ wst, unsigned short* __restrict__ qdst,
    const float* __restrict__ bq, int n0, int t)
{
    int w = t >> 6, l = t & 63;
    int wm = w >> 1, wn = w & 1;
    int l15 = l & 15, quad = l >> 4;
    int acol = (quad ^ ((l15 >> 1) & 3)) * 8;
    int rsw  = (l15 >> 1) & 3;

    f32x4 acc[2][8];
    #pragma unroll
    for (int i = 0; i < 2; i++)
        #pragma unroll
        for (int j = 0; j < 8; j++)
            #pragma unroll
            for (int r = 0; r < 4; r++) acc[i][j][r] = 0.f;

    stage_w(W, wst, 0, t);
    asm volatile("s_waitcnt vmcnt(0)" ::: "memory");
    __syncthreads();

    int buf = 0;
    for (int kt = 0; kt < 8; ++kt) {
        if (kt + 1 < 8) stage_w(W, wst + (buf^1)*8192, (kt+1)*32, t);
        __builtin_amdgcn_sched_barrier(0);
        bf16x8 af[2], bfr[8];
        #pragma unroll
        for (int i = 0; i < 2; i++) {
            int n = wm*32 + i*16 + l15;
            af[i] = *(const bf16x8*)(hs + n*256 + (kt*4 + (quad ^ rsw))*8);
        }
        #pragma unroll
        for (int j = 0; j < 8; j++)
            bfr[j] = *(const bf16x8*)(wst + buf*8192 + (wn*128 + j*16 + l15)*32 + acol);
        __builtin_amdgcn_s_setprio(1);
        #pragma unroll
        for (int i = 0; i < 2; i++)
            #pragma unroll
            for (int j = 0; j < 8; j++)
                acc[i][j] = __builtin_amdgcn_mfma_f32_16x16x32_bf16(af[i], bfr[j], acc[i][j], 0, 0, 0);
        __builtin_amdgcn_s_setprio(0);
        __builtin_amdgcn_sched_barrier(0);
        asm volatile("s_waitcnt vmcnt(0)" ::: "memory");
        __syncthreads();
        buf ^= 1;
    }

    // epilogue: two 32-row halves bounced through wst (ep[32][264] = 16.9KB)
    unsigned short* ep = wst;
    #pragma unroll
    for (int h = 0; h < 2; h++) {
        if (wm == h) {
            #pragma unroll
            for (int i = 0; i < 2; i++) {
                #pragma unroll
                for (int j = 0; j < 8; j++) {
                    int cl = wn*128 + j*16 + l15;
                    float bi = bq[cl];
                    #pragma unroll
                    for (int r = 0; r < 4; r++) {
                        int rloc = i*16 + quad*4 + r;    // 0..31
                        float val = acc[i][j][r] + bi;
                        val = val > 0.f ? val + 1.f : __expf(val);
                        ep[rloc*264 + cl] = f2bf(val);
                    }
                }
            }
        }
        __syncthreads();
        #pragma unroll
        for (int it = 0; it < 4; it++) {
            int idx = t + it*256;         // 0..1023
            int row = idx >> 5;           // 0..31
            int colc = (idx & 31) * 8;    // 0..248
            us8 vv = *(us8*)(ep + row*264 + colc);
            *(us8*)(qdst + (size_t)(n0 + h*32 + row)*256 + colc) = vv;
        }
        __syncthreads();
    }
}

__global__ __launch_bounds__(256, 2) void fused_qkv(
    const float* __restrict__ x, const float2* __restrict__ sums,
    const float* __restrict__ gamma, const float* __restrict__ beta,
    const unsigned short* __restrict__ wqb, const unsigned short* __restrict__ wkvb,
    const float* __restrict__ bq, const float* __restrict__ bkv,
    unsigned short* __restrict__ qT, unsigned short* __restrict__ kvbuf)
{
    __shared__ __align__(16) unsigned short hs[16384];    // 32KB h tile [64][256] swizzled
    __shared__ __align__(16) unsigned short wst[16384];   // 32KB = 2 x 16KB staging
    __shared__ float scale[256], shift[256];

    int b  = blockIdx.y;
    int n0 = blockIdx.x * 64;
    int t  = threadIdx.x;

    // GN coefficients (thread t = channel t)
    {
        int c = t, gbase = c & ~7;
        float s = 0.f, q = 0.f;
        #pragma unroll
        for (int j = 0; j < 8; j++) { float2 u = sums[b*256 + gbase + j]; s += u.x; q += u.y; }
        float mean = s * (1.f/32768.f);
        float var  = q * (1.f/32768.f) - mean*mean;
        float inv  = rsqrtf(var + 1e-6f);
        float gm = gamma[c] * inv;
        scale[c] = gm; shift[c] = beta[c] - mean*gm;
    }
    __syncthreads();

    // GN apply + transpose into hs: 8 iters x (32 c-rows, 8 threads/row x 8 n each)
    #pragma unroll
    for (int it = 0; it < 8; ++it) {
        int c  = it*32 + (t >> 3);
        int nl = (t & 7) * 8;
        const float* xp = x + ((size_t)(b*256 + c))*4096 + n0 + nl;
        float4 v0 = *(const float4*)xp;
        float4 v1 = *(const float4*)(xp + 4);
        float sc = scale[c], sh = shift[c];
        int chunk = c >> 3, pos = c & 7;
        float vv[8] = {v0.x, v0.y, v0.z, v0.w, v1.x, v1.y, v1.z, v1.w};
        #pragma unroll
        for (int r = 0; r < 8; ++r) {
            int n = nl + r;
            int cs = (chunk & ~3) | ((chunk & 3) ^ ((n >> 1) & 3));
            hs[n*256 + cs*8 + pos] = f2bf(vv[r] * sc + sh);
        }
    }
    __syncthreads();

    unsigned short* kvdst = kvbuf + (size_t)b * 2097152;
    phase_kv(wkvb,         hs, wst, kvdst, bkv,       0,   n0, true,  t);
    phase_kv(wkvb + 65536, hs, wst, kvdst, bkv + 256, 256, n0, false, t);
    phase_q (wqb,          hs, wst, qT + (size_t)b*1048576, bq, n0, t);
}

// ================= shared NT bf16 MFMA GEMM body (modes 3,4,5) =================
// 128x128 tile, BK=32, 4 waves, depth-2 counted-vmcnt pipeline, triple-buffered LDS,
// both-sides chunk swizzle.
template<int MODE>
__device__ __forceinline__ void gemm_body(
    const unsigned short* __restrict__ Ab, const unsigned short* __restrict__ Bb,
    const float* __restrict__ bias, const float* __restrict__ residb,
    void* __restrict__ Cb,
    int N, int K, int k0, int Ks, int m_blk, int n_blk, char* smem)
{
    unsigned short* lds = (unsigned short*)smem;

    int t = threadIdx.x;
    int w = t >> 6, l = t & 63;
    int wm = w >> 1, wn = w & 1;
    int l15 = l & 15, quad = l >> 4;

    int srow = w * 16 + (l >> 2);
    int skc  = (((l & 3) ^ ((l >> 3) & 3)) * 8);

    f32x4 acc[4][4];
    #pragma unroll
    for (int i = 0; i < 4; i++)
        #pragma unroll
        for (int j = 0; j < 4; j++)
            #pragma unroll
            for (int r = 0; r < 4; r++) acc[i][j][r] = 0.f;

    auto stage = [&](int buf, int kt) {
        unsigned short* Asl = lds + buf*8192 + t*8;
        unsigned short* Bsl = Asl + 4096;
        #pragma unroll
        for (int rep = 0; rep < 2; rep++) {
            gload_lds16(Ab + (size_t)(m_blk + rep*64 + srow) * K + kt + skc, Asl + rep*2048);
            gload_lds16(Bb + (size_t)(n_blk + rep*64 + srow) * K + kt + skc, Bsl + rep*2048);
        }
    };

    const int nt = Ks >> 5;

    stage(0, k0);
    if (nt > 1) stage(1, k0 + 32);

    int acol = (quad ^ ((l15 >> 1) & 3)) * 8;

    int bufc = 0;
    for (int kt = 0; kt < nt; ++kt) {
        if (kt + 1 < nt) asm volatile("s_waitcnt vmcnt(4)" ::: "memory");
        else             asm volatile("s_waitcnt vmcnt(0)" ::: "memory");
        __builtin_amdgcn_s_barrier();
        __builtin_amdgcn_sched_barrier(0);
        if (kt + 2 < nt) {
            int bufn = bufc + 2; if (bufn >= 3) bufn -= 3;
            stage(bufn, k0 + (kt + 2) * 32);
        }
        __builtin_amdgcn_sched_barrier(0);

        const unsigned short* Aw = lds + bufc*8192 + (wm*64 + l15)*32 + acol;
        const unsigned short* Bw = lds + bufc*8192 + 4096 + (wn*64 + l15)*32 + acol;
        bf16x8 af[4], bfr[4];
        #pragma unroll
        for (int i = 0; i < 4; i++) af[i]  = *(const bf16x8*)(Aw + i*512);
        #pragma unroll
        for (int j = 0; j < 4; j++) bfr[j] = *(const bf16x8*)(Bw + j*512);
        __builtin_amdgcn_s_setprio(1);
        #pragma unroll
        for (int i = 0; i < 4; i++)
            #pragma unroll
            for (int j = 0; j < 4; j++)
                acc[i][j] = __builtin_amdgcn_mfma_f32_16x16x32_bf16(af[i], bfr[j], acc[i][j], 0, 0, 0);
        __builtin_amdgcn_s_setprio(0);
        bufc = (bufc == 2) ? 0 : bufc + 1;
    }
    __syncthreads();

    if (MODE == 4) {
        unsigned short* ep = (unsigned short*)smem;
        unsigned short* Cp = (unsigned short*)Cb;
        #pragma unroll
        for (int h = 0; h < 2; h++) {
            if (wm == h) {
                int row0 = quad*4;
                int col0 = wn*64 + l15;
                #pragma unroll
                for (int i = 0; i < 4; i++)
                    #pragma unroll
                    for (int j = 0; j < 4; j++)
                        #pragma unroll
                        for (int r = 0; r < 4; r++)
                            ep[(row0 + i*16 + r)*136 + col0 + j*16] = f2bf(acc[i][j][r]);
            }
            __syncthreads();
            #pragma unroll
            for (int it = 0; it < 4; it++) {
                int row = it*16 + (t >> 4);
                int col = (t & 15) * 8;
                us8 vv = *(us8*)(ep + row*136 + col);
                *(us8*)(Cp + (size_t)(m_blk + h*64 + row) * N + n_blk + col) = vv;
            }
            __syncthreads();
        }
    } else {
        float* ep32 = (float*)smem;
        float* Cp = (float*)Cb;
        #pragma unroll
        for (int h = 0; h < 2; h++) {
            if (wm == h) {
                int row0 = quad*4;
                int col0 = wn*64 + l15;
                #pragma unroll
                for (int i = 0; i < 4; i++)
                    #pragma unroll
                    for (int j = 0; j < 4; j++)
                        #pragma unroll
                        for (int r = 0; r < 4; r++)
                            ep32[(row0 + i*16 + r)*140 + col0 + j*16] = acc[i][j][r];
            }
            __syncthreads();
            #pragma unroll
            for (int it = 0; it < 8; it++) {
                int rl  = it*8 + (t >> 5);
                int row = m_blk + h*64 + rl;
                int col = (t & 31) * 4;
                f32x4 vv = *(f32x4*)(ep32 + rl*140 + col);
                if (MODE == 5) {
                    float bi = bias[row];
                    float4 rv = *(const float4*)(residb + (size_t)row * N + n_blk + col);
                    vv[0] += bi + rv.x; vv[1] += bi + rv.y;
                    vv[2] += bi + rv.z; vv[3] += bi + rv.w;
                }
                *(f32x4*)(Cp + (size_t)row * N + n_blk + col) = vv;
            }
            __syncthreads();
        }
    }
}

template<int MODE>
__global__ __launch_bounds__(256) void gemm_nt(
    const unsigned short* __restrict__ A, const unsigned short* __restrict__ B,
    const float* __restrict__ bias, const float* __restrict__ resid,
    void* __restrict__ Cout,
    int N, int K, int splits,
    size_t sA, size_t sB, size_t sC, size_t sR, int elem4)
{
    __shared__ __align__(16) char smem[49152];
    int b  = blockIdx.z / splits;
    int sp = blockIdx.z % splits;
    int Ks = K / splits;
    size_t cbase = (MODE == 3) ? ((size_t)(b*splits + sp)) * sC : (size_t)b * sC;
    void* Cb = elem4 ? (void*)((float*)Cout + cbase) : (void*)((unsigned short*)Cout + cbase);
    gemm_body<MODE>(A + b*sA, B + b*sB, bias,
                    resid ? resid + b*sR : nullptr, Cb,
                    N, K, sp*Ks, Ks, blockIdx.y*128, blockIdx.x*128, smem);
}

extern "C" void kernel_launch(void* const* d_in, const int* in_sizes, int n_in,
                              void* d_out, int out_size, void* d_ws, size_t ws_size,
                              hipStream_t stream) {
    const float* x     = (const float*)d_in[0];
    const float* gamma = (const float*)d_in[1];
    const float* beta  = (const float*)d_in[2];
    const float* wq    = (const float*)d_in[3];
    const float* bq    = (const float*)d_in[4];
    const float* wk    = (const float*)d_in[5];
    const float* bk    = (const float*)d_in[6];
    const float* wv    = (const float*)d_in[7];
    const float* bv    = (const float*)d_in[8];
    const float* wo    = (const float*)d_in[9];
    const float* bo    = (const float*)d_in[10];
    float* out = (float*)d_out;

    const size_t TEN = (size_t)B_DIM * C_DIM * N_DIM;   // 8,388,608 elems
    unsigned short* ws16  = (unsigned short*)d_ws;
    unsigned short* hT    = ws16;                    // (unused after fusion; layout kept)
    unsigned short* qT    = hT    + TEN;             // [B][N][C] bf16
    unsigned short* kvbuf = qT    + TEN;             // [B][512][N] bf16 (k rows 0-255, v rows 256-511)
    unsigned short* kvb   = kvbuf + 2*TEN;           // [B][C][C] bf16
    unsigned short* M2b   = kvb   + 524288;          // [B][C][C] bf16
    unsigned short* wqb   = M2b   + 524288;
    unsigned short* wkvb  = wqb   + 65536;           // stacked [512][256]
    unsigned short* wob   = wkvb  + 131072;
    float*          bkv   = (float*)(wob + 65536);   // [512]
    float2*         sums  = (float2*)(bkv + 512);    // [B*C]
    float*          kvf   = (float*)(sums + 2048);   // [B][8][C*C] fp32 partials (16.8MB)

    // 1) prep: weights->bf16, bias concat, gn stats
    prep_kernel<<<dim3(2305), 256, 0, stream>>>(wq, wk, wv, wo, bk, bv, x,
                                                wqb, wkvb, wob, bkv, sums);
    // 2) fused GN + transpose + q/k/v projections
    fused_qkv<<<dim3(N_DIM/64, B_DIM), 256, 0, stream>>>(
        x, sums, gamma, beta, wqb, wkvb, bq, bkv, qT, kvbuf);
    // 3) kv[c][d] = sum_n k[c][n]*v[d][n]  M=256 N=256 K=4096, split-8 fp32
    gemm_nt<3><<<dim3(2, 2, B_DIM*8), 256, 0, stream>>>(
        kvbuf, kvbuf + 1048576, nullptr, nullptr, kvf,
        256, 4096, 8, 2097152, 2097152, 65536, 0, 1);
    // 4) reduce 8 partials -> kvb bf16
    kvred<<<dim3(512), 256, 0, stream>>>(kvf, kvb);
    // 5) M2[o][c] = sum_d wo[o][d]*kv[c][d]  M=256 N=256 K=256
    gemm_nt<4><<<dim3(2, 2, B_DIM), 256, 0, stream>>>(
        wob, kvb, nullptr, nullptr, M2b,
        256, 256, 1, 0, 65536, 65536, 0, 0);
    // 6) out[o][n] = sum_c M2[o][c]*qT[n][c] + bo[o] + x  M=256 N=4096 K=256
    gemm_nt<5><<<dim3(32, 2, B_DIM), 256, 0, stream>>>(
        M2b, qT, bo, x, out,
        4096, 256, 1, 65536, 1048576, 1048576, 1048576, 1);
}

// Round 9
// 172.689 us; speedup vs baseline: 1.0774x; 1.0069x over previous
//
#include <hip/hip_runtime.h>
#include <math.h>

#define C_DIM 256
#define N_DIM 4096
#define B_DIM 8

typedef __attribute__((ext_vector_type(8))) short bf16x8;
typedef __attribute__((ext_vector_type(4))) float f32x4;
typedef __attribute__((ext_vector_type(8))) unsigned short us8;
typedef __attribute__((ext_vector_type(4))) unsigned short us4;

__device__ inline unsigned short f2bf(float f) {
    unsigned int u = __float_as_uint(f);
    u += 0x7fffu + ((u >> 16) & 1u);       // round-to-nearest-even
    return (unsigned short)(u >> 16);
}

__device__ inline void gload_lds16(const void* g, void* l) {
    __builtin_amdgcn_global_load_lds(
        (const __attribute__((address_space(1))) unsigned int*)g,
        (__attribute__((address_space(3))) unsigned int*)l, 16, 0, 0);
}

// ---------------- prep: weight cvt + bias concat + gn per-channel stats ----------------
__global__ __launch_bounds__(256) void prep_kernel(
    const float* __restrict__ wq, const float* __restrict__ wk,
    const float* __restrict__ wv, const float* __restrict__ wo,
    const float* __restrict__ bk, const float* __restrict__ bv,
    const float* __restrict__ x,
    unsigned short* __restrict__ wqb, unsigned short* __restrict__ wkvb,
    unsigned short* __restrict__ wob, float* __restrict__ bkv,
    float2* __restrict__ sums)
{
    int z = blockIdx.x;
    int t = threadIdx.x;
    if (z < 256) {
        const float* s; unsigned short* d;
        int which = z >> 6;
        if (which == 0)      { s = wq; d = wqb; }
        else if (which == 1) { s = wk; d = wkvb; }
        else if (which == 2) { s = wv; d = wkvb + 65536; }
        else                 { s = wo; d = wob; }
        int idx = (z & 63) * 1024 + t * 4;
        float4 v = *(const float4*)(s + idx);
        us4 r; r[0] = f2bf(v.x); r[1] = f2bf(v.y); r[2] = f2bf(v.z); r[3] = f2bf(v.w);
        *(us4*)(d + idx) = r;
    } else if (z == 256) {
        bkv[t]       = bk[t];
        bkv[t + 256] = bv[t];
    } else {
        int bc = z - 257;
        const float* xc = x + (size_t)bc * N_DIM;
        float s = 0.f, q = 0.f;
        for (int i = t; i < 1024; i += 256) {
            float4 v = ((const float4*)xc)[i];
            s += v.x + v.y + v.z + v.w;
            q += v.x*v.x + v.y*v.y + v.z*v.z + v.w*v.w;
        }
        #pragma unroll
        for (int off = 32; off > 0; off >>= 1) {
            s += __shfl_down(s, off);
            q += __shfl_down(q, off);
        }
        __shared__ float red[8];
        int w = t >> 6;
        if ((t & 63) == 0) { red[w*2] = s; red[w*2+1] = q; }
        __syncthreads();
        if (t == 0) {
            sums[bc] = make_float2(red[0]+red[2]+red[4]+red[6],
                                   red[1]+red[3]+red[5]+red[7]);
        }
    }
}

// ---------------- kv split-K reduce + cvt (8 splits) ----------------
__global__ __launch_bounds__(256) void kvred(const float* __restrict__ src, unsigned short* __restrict__ dst) {
    int gi = (blockIdx.x * 256 + threadIdx.x) * 4;
    int b = gi >> 16, idx = gi & 65535;
    float4 a = make_float4(0.f,0.f,0.f,0.f);
    #pragma unroll
    for (int sp = 0; sp < 8; sp++) {
        float4 v = *(const float4*)(src + (((size_t)b*8 + sp) << 16) + idx);
        a.x += v.x; a.y += v.y; a.z += v.z; a.w += v.w;
    }
    us4 r; r[0] = f2bf(a.x); r[1] = f2bf(a.y); r[2] = f2bf(a.z); r[3] = f2bf(a.w);
    *(us4*)(dst + ((size_t)b << 16) + idx) = r;
}

// ================= fused GN + transpose + Q/K/V projections (3 blocks/CU) =================
// LDS 50KB: hs 32KB GN'd h tile [64 n][256 k] with 3-bit chunk swizzle
// (cs = (c&~7)|((c&7)^((n>>1)&7)) -> 8 slots x 2 lanes = conflict-free frag reads),
// wst 16KB SINGLE-buffer weight staging (R4 involution), coeffs 2KB.
// Phases K (elu) / V / Q, each 8 BK=32 steps; per step: ds_read+16 MFMA, barrier,
// stage next slab, barrier (serial drain — cross-block wave overlap covers it).
// K/V epilogue: 4 quarter-rounds through wst (ep 64x72). Q epilogue: through hs (dead).

__device__ __forceinline__ void stage_w(const unsigned short* __restrict__ W,
                                        unsigned short* __restrict__ dst, int kt, int t) {
    #pragma unroll
    for (int s = 0; s < 4; s++) {
        int c = t + s*256;            // 0..1023 16B-chunks
        int row = c >> 2, slot = c & 3;
        int cs = slot ^ ((row >> 1) & 3);
        gload_lds16(W + (size_t)row*256 + kt + cs*8, dst + c*8);
    }
}

__device__ __forceinline__ void phase_kv2(
    const unsigned short* __restrict__ W, const unsigned short* __restrict__ hs,
    unsigned short* __restrict__ wst, unsigned short* __restrict__ kvdst,
    const float* __restrict__ biasr, int ccb, int n0, bool elu, int t)
{
    int w = t >> 6, l = t & 63;
    int wm = w >> 1, wn = w & 1;
    int l15 = l & 15, quad = l >> 4;
    int wcol = (quad ^ ((l15 >> 1) & 3)) * 8;
    int rsw8 = (l15 >> 1) & 7;

    f32x4 acc[8][2];
    #pragma unroll
    for (int i = 0; i < 8; i++)
        #pragma unroll
        for (int j = 0; j < 2; j++)
            #pragma unroll
            for (int r = 0; r < 4; r++) acc[i][j][r] = 0.f;

    for (int kt = 0; kt < 8; ++kt) {
        bf16x8 af[8], bfr[2];
        #pragma unroll
        for (int i = 0; i < 8; i++)
            af[i] = *(const bf16x8*)(wst + (wm*128 + i*16 + l15)*32 + wcol);
        int coff = ((kt & ~1)*4 + (((kt & 1)*4 + quad) ^ rsw8)) * 8;
        #pragma unroll
        for (int j = 0; j < 2; j++) {
            int n = wn*32 + j*16 + l15;
            bfr[j] = *(const bf16x8*)(hs + n*256 + coff);
        }
        __builtin_amdgcn_s_setprio(1);
        #pragma unroll
        for (int i = 0; i < 8; i++)
            #pragma unroll
            for (int j = 0; j < 2; j++)
                acc[i][j] = __builtin_amdgcn_mfma_f32_16x16x32_bf16(af[i], bfr[j], acc[i][j], 0, 0, 0);
        __builtin_amdgcn_s_setprio(0);
        __syncthreads();                          // all waves done reading wst[kt]
        if (kt < 7) {
            stage_w(W, wst, (kt+1)*32, t);
            __syncthreads();                      // drain + publish wst[kt+1]
        }
    }

    // epilogue: 4 quarter-rounds through wst (ep[64][72] = 9.2KB)
    unsigned short* ep = wst;
    #pragma unroll
    for (int rd = 0; rd < 4; ++rd) {
        int wmsel = rd >> 1, h2 = rd & 1;
        if (wm == wmsel) {
            #pragma unroll
            for (int i2 = 0; i2 < 4; i2++) {
                int i = h2*4 + i2;
                #pragma unroll
                for (int j = 0; j < 2; j++) {
                    int cl = wn*32 + j*16 + l15;
                    #pragma unroll
                    for (int r = 0; r < 4; r++) {
                        int rloc = i2*16 + quad*4 + r;
                        float val = acc[i][j][r] + biasr[wmsel*128 + h2*64 + rloc];
                        if (elu) val = val > 0.f ? val + 1.f : __expf(val);
                        ep[rloc*72 + cl] = f2bf(val);
                    }
                }
            }
        }
        __syncthreads();
        #pragma unroll
        for (int it = 0; it < 2; it++) {
            int idx = t + it*256;                 // 0..511
            int row = idx >> 3, colc = (idx & 7) * 8;
            us8 vv = *(us8*)(ep + row*72 + colc);
            *(us8*)(kvdst + (size_t)(ccb + wmsel*128 + h2*64 + row)*4096 + n0 + colc) = vv;
        }
        __syncthreads();
    }
}

__device__ __forceinline__ void phase_q2(
    const unsigned short* __restrict__ W, unsigned short* __restrict__ hs,
    unsigned short* __restrict__ wst, unsigned short* __restrict__ qdst,
    const float* __restrict__ bq, int n0, int t)
{
    int w = t >> 6, l = t & 63;
    int wm = w >> 1, wn = w & 1;
    int l15 = l & 15, quad = l >> 4;
    int wcol = (quad ^ ((l15 >> 1) & 3)) * 8;
    int rsw8 = (l15 >> 1) & 7;

    f32x4 acc[2][8];
    #pragma unroll
    for (int i = 0; i < 2; i++)
        #pragma unroll
        for (int j = 0; j < 8; j++)
            #pragma unroll
            for (int r = 0; r < 4; r++) acc[i][j][r] = 0.f;

    for (int kt = 0; kt < 8; ++kt) {
        bf16x8 af[2], bfr[8];
        int coff = ((kt & ~1)*4 + (((kt & 1)*4 + quad) ^ rsw8)) * 8;
        #pragma unroll
        for (int i = 0; i < 2; i++) {
            int n = wm*32 + i*16 + l15;
            af[i] = *(const bf16x8*)(hs + n*256 + coff);
        }
        #pragma unroll
        for (int j = 0; j < 8; j++)
            bfr[j] = *(const bf16x8*)(wst + (wn*128 + j*16 + l15)*32 + wcol);
        __builtin_amdgcn_s_setprio(1);
        #pragma unroll
        for (int i = 0; i < 2; i++)
            #pragma unroll
            for (int j = 0; j < 8; j++)
                acc[i][j] = __builtin_amdgcn_mfma_f32_16x16x32_bf16(af[i], bfr[j], acc[i][j], 0, 0, 0);
        __builtin_amdgcn_s_setprio(0);
        __syncthreads();
        if (kt < 7) {
            stage_w(W, wst, (kt+1)*32, t);
            __syncthreads();
        }
    }

    // epilogue through hs (dead after last step): ep[32][264] = 16.9KB
    unsigned short* ep = hs;
    #pragma unroll
    for (int h = 0; h < 2; h++) {
        if (wm == h) {
            #pragma unroll
            for (int i = 0; i < 2; i++) {
                #pragma unroll
                for (int j = 0; j < 8; j++) {
                    int cl = wn*128 + j*16 + l15;
                    float bi = bq[cl];
                    #pragma unroll
                    for (int r = 0; r < 4; r++) {
                        int rloc = i*16 + quad*4 + r;    // 0..31
                        float val = acc[i][j][r] + bi;
                        val = val > 0.f ? val + 1.f : __expf(val);
                        ep[rloc*264 + cl] = f2bf(val);
                    }
                }
            }
        }
        __syncthreads();
        #pragma unroll
        for (int it = 0; it < 4; it++) {
            int idx = t + it*256;         // 0..1023
            int row = idx >> 5;           // 0..31
            int colc = (idx & 31) * 8;    // 0..248
            us8 vv = *(us8*)(ep + row*264 + colc);
            *(us8*)(qdst + (size_t)(n0 + h*32 + row)*256 + colc) = vv;
        }
        __syncthreads();
    }
}

__global__ __launch_bounds__(256) void fused_qkv(
    const float* __restrict__ x, const float2* __restrict__ sums,
    const float* __restrict__ gamma, const float* __restrict__ beta,
    const unsigned short* __restrict__ wqb, const unsigned short* __restrict__ wkvb,
    const float* __restrict__ bq, const float* __restrict__ bkv,
    unsigned short* __restrict__ qT, unsigned short* __restrict__ kvbuf)
{
    __shared__ __align__(16) unsigned short hs[16384];    // 32KB h tile [64][256] swizzled
    __shared__ __align__(16) unsigned short wst[8192];    // 16KB single weight buffer
    __shared__ float scale[256], shift[256];

    int b  = blockIdx.y;
    int n0 = blockIdx.x * 64;
    int t  = threadIdx.x;

    // stage K-phase slab 0 early — overlaps the GN fill below
    stage_w(wkvb, wst, 0, t);

    // GN coefficients (thread t = channel t)
    {
        int c = t, gbase = c & ~7;
        float s = 0.f, q = 0.f;
        #pragma unroll
        for (int j = 0; j < 8; j++) { float2 u = sums[b*256 + gbase + j]; s += u.x; q += u.y; }
        float mean = s * (1.f/32768.f);
        float var  = q * (1.f/32768.f) - mean*mean;
        float inv  = rsqrtf(var + 1e-6f);
        float gm = gamma[c] * inv;
        scale[c] = gm; shift[c] = beta[c] - mean*gm;
    }
    __syncthreads();

    // GN apply + transpose into hs (3-bit chunk swizzle)
    #pragma unroll
    for (int it = 0; it < 8; ++it) {
        int c  = it*32 + (t >> 3);
        int nl = (t & 7) * 8;
        const float* xp = x + ((size_t)(b*256 + c))*4096 + n0 + nl;
        float4 v0 = *(const float4*)xp;
        float4 v1 = *(const float4*)(xp + 4);
        float sc = scale[c], sh = shift[c];
        int chunk = c >> 3, pos = c & 7;
        float vv[8] = {v0.x, v0.y, v0.z, v0.w, v1.x, v1.y, v1.z, v1.w};
        #pragma unroll
        for (int r = 0; r < 8; ++r) {
            int n = nl + r;
            int cs = (chunk & ~7) | ((chunk & 7) ^ ((n >> 1) & 7));
            hs[n*256 + cs*8 + pos] = f2bf(vv[r] * sc + sh);
        }
    }
    __syncthreads();   // publishes hs AND (drains vmcnt) wst slab 0

    unsigned short* kvdst = kvbuf + (size_t)b * 2097152;
    phase_kv2(wkvb,         hs, wst, kvdst, bkv,       0,   n0, true,  t);
    stage_w(wkvb + 65536, wst, 0, t);
    __syncthreads();
    phase_kv2(wkvb + 65536, hs, wst, kvdst, bkv + 256, 256, n0, false, t);
    stage_w(wqb, wst, 0, t);
    __syncthreads();
    phase_q2(wqb, hs, wst, qT + (size_t)b*1048576, bq, n0, t);
}

// ================= shared NT bf16 MFMA GEMM body (modes 3,4,5) =================
// 128x128 tile, BK=32, 4 waves, depth-2 counted-vmcnt pipeline, triple-buffered LDS,
// both-sides chunk swizzle.
template<int MODE>
__device__ __forceinline__ void gemm_body(
    const unsigned short* __restrict__ Ab, const unsigned short* __restrict__ Bb,
    const float* __restrict__ bias, const float* __restrict__ residb,
    void* __restrict__ Cb,
    int N, int K, int k0, int Ks, int m_blk, int n_blk, char* smem)
{
    unsigned short* lds = (unsigned short*)smem;

    int t = threadIdx.x;
    int w = t >> 6, l = t & 63;
    int wm = w >> 1, wn = w & 1;
    int l15 = l & 15, quad = l >> 4;

    int srow = w * 16 + (l >> 2);
    int skc  = (((l & 3) ^ ((l >> 3) & 3)) * 8);

    f32x4 acc[4][4];
    #pragma unroll
    for (int i = 0; i < 4; i++)
        #pragma unroll
        for (int j = 0; j < 4; j++)
            #pragma unroll
            for (int r = 0; r < 4; r++) acc[i][j][r] = 0.f;

    auto stage = [&](int buf, int kt) {
        unsigned short* Asl = lds + buf*8192 + t*8;
        unsigned short* Bsl = Asl + 4096;
        #pragma unroll
        for (int rep = 0; rep < 2; rep++) {
            gload_lds16(Ab + (size_t)(m_blk + rep*64 + srow) * K + kt + skc, Asl + rep*2048);
            gload_lds16(Bb + (size_t)(n_blk + rep*64 + srow) * K + kt + skc, Bsl + rep*2048);
        }
    };

    const int nt = Ks >> 5;

    stage(0, k0);
    if (nt > 1) stage(1, k0 + 32);

    int acol = (quad ^ ((l15 >> 1) & 3)) * 8;

    int bufc = 0;
    for (int kt = 0; kt < nt; ++kt) {
        if (kt + 1 < nt) asm volatile("s_waitcnt vmcnt(4)" ::: "memory");
        else             asm volatile("s_waitcnt vmcnt(0)" ::: "memory");
        __builtin_amdgcn_s_barrier();
        __builtin_amdgcn_sched_barrier(0);
        if (kt + 2 < nt) {
            int bufn = bufc + 2; if (bufn >= 3) bufn -= 3;
            stage(bufn, k0 + (kt + 2) * 32);
        }
        __builtin_amdgcn_sched_barrier(0);

        const unsigned short* Aw = lds + bufc*8192 + (wm*64 + l15)*32 + acol;
        const unsigned short* Bw = lds + bufc*8192 + 4096 + (wn*64 + l15)*32 + acol;
        bf16x8 af[4], bfr[4];
        #pragma unroll
        for (int i = 0; i < 4; i++) af[i]  = *(const bf16x8*)(Aw + i*512);
        #pragma unroll
        for (int j = 0; j < 4; j++) bfr[j] = *(const bf16x8*)(Bw + j*512);
        __builtin_amdgcn_s_setprio(1);
        #pragma unroll
        for (int i = 0; i < 4; i++)
            #pragma unroll
            for (int j = 0; j < 4; j++)
                acc[i][j] = __builtin_amdgcn_mfma_f32_16x16x32_bf16(af[i], bfr[j], acc[i][j], 0, 0, 0);
        __builtin_amdgcn_s_setprio(0);
        bufc = (bufc == 2) ? 0 : bufc + 1;
    }
    __syncthreads();

    if (MODE == 4) {
        unsigned short* ep = (unsigned short*)smem;
        unsigned short* Cp = (unsigned short*)Cb;
        #pragma unroll
        for (int h = 0; h < 2; h++) {
            if (wm == h) {
                int row0 = quad*4;
                int col0 = wn*64 + l15;
                #pragma unroll
                for (int i = 0; i < 4; i++)
                    #pragma unroll
                    for (int j = 0; j < 4; j++)
                        #pragma unroll
                        for (int r = 0; r < 4; r++)
                            ep[(row0 + i*16 + r)*136 + col0 + j*16] = f2bf(acc[i][j][r]);
            }
            __syncthreads();
            #pragma unroll
            for (int it = 0; it < 4; it++) {
                int row = it*16 + (t >> 4);
                int col = (t & 15) * 8;
                us8 vv = *(us8*)(ep + row*136 + col);
                *(us8*)(Cp + (size_t)(m_blk + h*64 + row) * N + n_blk + col) = vv;
            }
            __syncthreads();
        }
    } else {
        float* ep32 = (float*)smem;
        float* Cp = (float*)Cb;
        #pragma unroll
        for (int h = 0; h < 2; h++) {
            if (wm == h) {
                int row0 = quad*4;
                int col0 = wn*64 + l15;
                #pragma unroll
                for (int i = 0; i < 4; i++)
                    #pragma unroll
                    for (int j = 0; j < 4; j++)
                        #pragma unroll
                        for (int r = 0; r < 4; r++)
                            ep32[(row0 + i*16 + r)*140 + col0 + j*16] = acc[i][j][r];
            }
            __syncthreads();
            #pragma unroll
            for (int it = 0; it < 8; it++) {
                int rl  = it*8 + (t >> 5);
                int row = m_blk + h*64 + rl;
                int col = (t & 31) * 4;
                f32x4 vv = *(f32x4*)(ep32 + rl*140 + col);
                if (MODE == 5) {
                    float bi = bias[row];
                    float4 rv = *(const float4*)(residb + (size_t)row * N + n_blk + col);
                    vv[0] += bi + rv.x; vv[1] += bi + rv.y;
                    vv[2] += bi + rv.z; vv[3] += bi + rv.w;
                }
                *(f32x4*)(Cp + (size_t)row * N + n_blk + col) = vv;
            }
            __syncthreads();
        }
    }
}

template<int MODE>
__global__ __launch_bounds__(256) void gemm_nt(
    const unsigned short* __restrict__ A, const unsigned short* __restrict__ B,
    const float* __restrict__ bias, const float* __restrict__ resid,
    void* __restrict__ Cout,
    int N, int K, int splits,
    size_t sA, size_t sB, size_t sC, size_t sR, int elem4)
{
    __shared__ __align__(16) char smem[49152];
    int b  = blockIdx.z / splits;
    int sp = blockIdx.z % splits;
    int Ks = K / splits;
    size_t cbase = (MODE == 3) ? ((size_t)(b*splits + sp)) * sC : (size_t)b * sC;
    void* Cb = elem4 ? (void*)((float*)Cout + cbase) : (void*)((unsigned short*)Cout + cbase);
    gemm_body<MODE>(A + b*sA, B + b*sB, bias,
                    resid ? resid + b*sR : nullptr, Cb,
                    N, K, sp*Ks, Ks, blockIdx.y*128, blockIdx.x*128, smem);
}

extern "C" void kernel_launch(void* const* d_in, const int* in_sizes, int n_in,
                              void* d_out, int out_size, void* d_ws, size_t ws_size,
                              hipStream_t stream) {
    const float* x     = (const float*)d_in[0];
    const float* gamma = (const float*)d_in[1];
    const float* beta  = (const float*)d_in[2];
    const float* wq    = (const float*)d_in[3];
    const float* bq    = (const float*)d_in[4];
    const float* wk    = (const float*)d_in[5];
    const float* bk    = (const float*)d_in[6];
    const float* wv    = (const float*)d_in[7];
    const float* bv    = (const float*)d_in[8];
    const float* wo    = (const float*)d_in[9];
    const float* bo    = (const float*)d_in[10];
    float* out = (float*)d_out;

    const size_t TEN = (size_t)B_DIM * C_DIM * N_DIM;   // 8,388,608 elems
    unsigned short* ws16  = (unsigned short*)d_ws;
    unsigned short* hT    = ws16;                    // (unused after fusion; layout kept)
    unsigned short* qT    = hT    + TEN;             // [B][N][C] bf16
    unsigned short* kvbuf = qT    + TEN;             // [B][512][N] bf16 (k rows 0-255, v rows 256-511)
    unsigned short* kvb   = kvbuf + 2*TEN;           // [B][C][C] bf16
    unsigned short* M2b   = kvb   + 524288;          // [B][C][C] bf16
    unsigned short* wqb   = M2b   + 524288;
    unsigned short* wkvb  = wqb   + 65536;           // stacked [512][256]
    unsigned short* wob   = wkvb  + 131072;
    float*          bkv   = (float*)(wob + 65536);   // [512]
    float2*         sums  = (float2*)(bkv + 512);    // [B*C]
    float*          kvf   = (float*)(sums + 2048);   // [B][8][C*C] fp32 partials (16.8MB)

    // 1) prep: weights->bf16, bias concat, gn stats
    prep_kernel<<<dim3(2305), 256, 0, stream>>>(wq, wk, wv, wo, bk, bv, x,
                                                wqb, wkvb, wob, bkv, sums);
    // 2) fused GN + transpose + q/k/v projections (3 blocks/CU)
    fused_qkv<<<dim3(N_DIM/64, B_DIM), 256, 0, stream>>>(
        x, sums, gamma, beta, wqb, wkvb, bq, bkv, qT, kvbuf);
    // 3) kv[c][d] = sum_n k[c][n]*v[d][n]  M=256 N=256 K=4096, split-8 fp32
    gemm_nt<3><<<dim3(2, 2, B_DIM*8), 256, 0, stream>>>(
        kvbuf, kvbuf + 1048576, nullptr, nullptr, kvf,
        256, 4096, 8, 2097152, 2097152, 65536, 0, 1);
    // 4) reduce 8 partials -> kvb bf16
    kvred<<<dim3(512), 256, 0, stream>>>(kvf, kvb);
    // 5) M2[o][c] = sum_d wo[o][d]*kv[c][d]  M=256 N=256 K=256
    gemm_nt<4><<<dim3(2, 2, B_DIM), 256, 0, stream>>>(
        wob, kvb, nullptr, nullptr, M2b,
        256, 256, 1, 0, 65536, 65536, 0, 0);
    // 6) out[o][n] = sum_c M2[o][c]*qT[n][c] + bo[o] + x  M=256 N=4096 K=256
    gemm_nt<5><<<dim3(32, 2, B_DIM), 256, 0, stream>>>(
        M2b, qT, bo, x, out,
        4096, 256, 1, 65536, 1048576, 1048576, 1048576, 1);
}